// Round 1
// 1447.884 us; speedup vs baseline: 1.0808x; 1.0808x over previous
//
#include <hip/hip_runtime.h>
#include <math.h>

// Static feature buffer: 9216 images x 400 feats.
// [0, 1024)    : features of img[n]
// [1024, 9216) : features of train[refs[n*8+s]] at offset 1024 + n*8 + s
__device__ float g_feat[9216 * 400];

// ---------------------------------------------------------------------------
// Kernel 1: LeNet trunk, one block per image.
// LDS layout (both tiles XOR-swizzled on 16B slots by row&7 to kill bank
// conflicts while keeping every read an aligned b128):
//   s_in : [3][32][32] floats, addr = ic*1024 + row*32 + ((slot^(row&7))<<2)+w
//   s_p1 : [6][14][32] floats (14 cols used), same swizzle keyed on row
// conv1: 98 threads, thread=(row-pair, 4-col tile), all 6 oc in registers,
//        weights via lane-uniform (scalar) loads, pool1 fused in-register.
// conv2: 160 threads, thread=(oc, oy), 10-wide row in registers,
//        pool2 fused via one __shfl_down.
// ---------------------------------------------------------------------------
__global__ __launch_bounds__(256, 4) void lenet_kernel(
    const float* __restrict__ img,     // (1024,3,32,32)
    const float* __restrict__ train,   // (50000,3,32,32)
    const int* __restrict__ refs,      // (1024,8)
    const float* __restrict__ w1, const float* __restrict__ b1,  // (6,3,5,5),(6)
    const float* __restrict__ w2, const float* __restrict__ b2)  // (16,6,5,5),(16)
{
    __shared__ __align__(16) float s_in[3 * 32 * 32];   // 12 KB, swizzled
    __shared__ __align__(16) float s_p1[6 * 14 * 32];   // 10.5 KB, swizzled

    const int blk = blockIdx.x;
    const int tid = threadIdx.x;

    const float* src = (blk < 1024)
        ? (img + (size_t)blk * 3072)
        : (train + (size_t)refs[blk - 1024] * 3072);
    const float4* src4 = (const float4*)src;

    // stage image, 3 float4 per thread, swizzled store (each f4 = one 16B slot)
    #pragma unroll
    for (int j = 0; j < 3; ++j) {
        const int i4 = tid + j * 256;            // 0..767
        const float4 v = src4[i4];
        const int ic   = i4 >> 8;
        const int row  = (i4 >> 3) & 31;
        const int slot = i4 & 7;
        *(float4*)(s_in + ic * 1024 + row * 32 + ((slot ^ (row & 7)) << 2)) = v;
    }
    __syncthreads();

    // ---- conv1 + relu + pool1 (fused). threads: (py 0..13, xt 0..6) = 98
    if (tid < 98) {
        const int py = tid / 7;
        const int xt = tid - py * 7;     // 4-col tile index; ox4 = 4*xt
        const int r0 = py * 2;           // first conv-output row of this thread

        float acc[6][2][4];
        #pragma unroll
        for (int oc = 0; oc < 6; ++oc) {
            const float b = b1[oc];      // lane-uniform -> scalar
            #pragma unroll
            for (int r = 0; r < 2; ++r)
                #pragma unroll
                for (int j = 0; j < 4; ++j) acc[oc][r][j] = b;
        }

        for (int ic = 0; ic < 3; ++ic) {
            const float* base = s_in + ic * 1024;
            const float* wic  = w1 + ic * 25;   // lane-uniform weight base
            float A[8], B[8];
            {
                const int row = r0, r7 = row & 7;
                const float4 lo = *(const float4*)(base + row * 32 + ((xt ^ r7) << 2));
                const float4 hi = *(const float4*)(base + row * 32 + (((xt + 1) ^ r7) << 2));
                A[0]=lo.x; A[1]=lo.y; A[2]=lo.z; A[3]=lo.w;
                A[4]=hi.x; A[5]=hi.y; A[6]=hi.z; A[7]=hi.w;
            }
            #pragma unroll
            for (int ky = 0; ky < 5; ++ky) {
                const int row = r0 + ky + 1, r7 = row & 7;
                const float4 lo = *(const float4*)(base + row * 32 + ((xt ^ r7) << 2));
                const float4 hi = *(const float4*)(base + row * 32 + (((xt + 1) ^ r7) << 2));
                B[0]=lo.x; B[1]=lo.y; B[2]=lo.z; B[3]=lo.w;
                B[4]=hi.x; B[5]=hi.y; B[6]=hi.z; B[7]=hi.w;
                #pragma unroll
                for (int oc = 0; oc < 6; ++oc) {
                    #pragma unroll
                    for (int kx = 0; kx < 5; ++kx) {
                        const float w = wic[oc * 75 + ky * 5 + kx];  // uniform -> s_load
                        #pragma unroll
                        for (int j = 0; j < 4; ++j) {
                            acc[oc][0][j] = fmaf(A[j + kx], w, acc[oc][0][j]);  // out row r0   <- in row r0+ky
                            acc[oc][1][j] = fmaf(B[j + kx], w, acc[oc][1][j]);  // out row r0+1 <- in row r0+ky+1
                        }
                    }
                }
                #pragma unroll
                for (int q = 0; q < 8; ++q) A[q] = B[q];  // input-row reuse across ky
            }
        }

        // 2x2 pool + relu -> s_p1[oc][py][2*xt .. 2*xt+1] (swizzled, float2)
        const int r7 = py & 7;
        const int px0 = xt * 2;   // even -> pair stays inside one 16B slot
        #pragma unroll
        for (int oc = 0; oc < 6; ++oc) {
            const float m0 = fmaxf(fmaxf(acc[oc][0][0], acc[oc][0][1]),
                                   fmaxf(acc[oc][1][0], acc[oc][1][1]));
            const float m1 = fmaxf(fmaxf(acc[oc][0][2], acc[oc][0][3]),
                                   fmaxf(acc[oc][1][2], acc[oc][1][3]));
            float* d = s_p1 + oc * 448 + py * 32 + (((px0 >> 2) ^ r7) << 2) + (px0 & 3);
            *(float2*)d = make_float2(fmaxf(m0, 0.0f), fmaxf(m1, 0.0f));
        }
    }
    __syncthreads();

    // ---- conv2 + relu + pool2 (fused). threads: (oc 0..15, oy 0..9) = 160
    if (tid < 160) {
        const int oc = tid / 10;
        const int oy = tid - oc * 10;

        float acc[10];
        {
            const float b = b2[oc];
            #pragma unroll
            for (int j = 0; j < 10; ++j) acc[j] = b;
        }
        const float* wrow = w2 + oc * 150;
        for (int ic = 0; ic < 6; ++ic) {
            const float* base = s_p1 + ic * 448;
            const float* wic  = wrow + ic * 25;
            #pragma unroll
            for (int ky = 0; ky < 5; ++ky) {
                const int row = oy + ky, r7 = row & 7;
                const float* rb = base + row * 32;
                float in[14];
                const float4 q0 = *(const float4*)(rb + ((0 ^ r7) << 2));
                const float4 q1 = *(const float4*)(rb + ((1 ^ r7) << 2));
                const float4 q2 = *(const float4*)(rb + ((2 ^ r7) << 2));
                const float2 q3 = *(const float2*)(rb + ((3 ^ r7) << 2));
                in[0]=q0.x;  in[1]=q0.y;  in[2]=q0.z;  in[3]=q0.w;
                in[4]=q1.x;  in[5]=q1.y;  in[6]=q1.z;  in[7]=q1.w;
                in[8]=q2.x;  in[9]=q2.y;  in[10]=q2.z; in[11]=q2.w;
                in[12]=q3.x; in[13]=q3.y;
                #pragma unroll
                for (int kx = 0; kx < 5; ++kx) {
                    const float w = wic[ky * 5 + kx];   // per-lane (oc-varying), L1-hot
                    #pragma unroll
                    for (int j = 0; j < 10; ++j)
                        acc[j] = fmaf(in[j + kx], w, acc[j]);
                }
            }
        }
        // horizontal pool in-lane, vertical via neighbor lane (oy, oy+1 same wave)
        float v[5];
        #pragma unroll
        for (int k = 0; k < 5; ++k) v[k] = fmaxf(acc[2 * k], acc[2 * k + 1]);
        float* fo = g_feat + (size_t)blk * 400 + oc * 25 + (oy >> 1) * 5;
        #pragma unroll
        for (int k = 0; k < 5; ++k) {
            const float m = fmaxf(v[k], __shfl_down(v[k], 1));
            if ((oy & 1) == 0) fo[k] = fmaxf(m, 0.0f);
        }
    }
}

// ---------------------------------------------------------------------------
// Kernel 2: head. One block per n. Phase A computes the 228 length-400 dots
// (x:12, ref_x:96, grad:120) with 16-lane k-parallel float4 groups so both
// weight and feature traffic is coalesced; shuffle-reduce inside the group.
// ---------------------------------------------------------------------------
__global__ __launch_bounds__(256) void head_kernel(
    const float* __restrict__ mem,   // (50000,10)
    const float* __restrict__ Wf, const float* __restrict__ bf,   // (12,400),(12)
    const float* __restrict__ Wg, const float* __restrict__ bg,   // (120,400),(120)
    const float* __restrict__ Wm, const float* __restrict__ bm,   // (10,10),(10)
    const int* __restrict__ refs,    // (1024,8)
    float* __restrict__ out)         // (1024,10)
{
    const int n = blockIdx.x;
    const int tid = threadIdx.x;

    __shared__ __align__(16) float s_feat[400];
    __shared__ __align__(16) float s_rfeat[8 * 400];
    __shared__ float s_x[12];
    __shared__ float s_rx[96];       // t = s*12 + h
    __shared__ float s_grad[120];    // g = h*10 + c
    __shared__ float s_diff[96];
    __shared__ float s_dist[8];
    __shared__ float s_logits[80];

    const float4* f4 = (const float4*)(g_feat + (size_t)n * 400);
    for (int i = tid; i < 100; i += 256) ((float4*)s_feat)[i] = f4[i];
    const float4* r4 = (const float4*)(g_feat + (size_t)(1024 + n * 8) * 400);
    for (int i = tid; i < 800; i += 256) ((float4*)s_rfeat)[i] = r4[i];
    __syncthreads();

    // Phase A: outputs o: [0,12)=x[h], [12,108)=rx[s*12+h], [108,228)=grad[g]
    const int grp = tid >> 4;   // 16 groups
    const int l16 = tid & 15;
    for (int r = 0; r < 15; ++r) {
        const int o = r * 16 + grp;
        if (o < 228) {
            const float* w;
            const float* f;
            if (o < 12)       { w = Wf + o * 400;              f = s_feat; }
            else if (o < 108) { const int t = o - 12;
                                w = Wf + (t % 12) * 400;       f = s_rfeat + (t / 12) * 400; }
            else              { const int g = o - 108;
                                w = Wg + g * 400;              f = s_feat; }
            float a = 0.0f;
            #pragma unroll
            for (int it = 0; it < 7; ++it) {
                const int k = it * 64 + l16 * 4;
                if (k < 400) {
                    const float4 wv = *(const float4*)(w + k);
                    const float4 fv = *(const float4*)(f + k);
                    a = fmaf(wv.x, fv.x, a); a = fmaf(wv.y, fv.y, a);
                    a = fmaf(wv.z, fv.z, a); a = fmaf(wv.w, fv.w, a);
                }
            }
            #pragma unroll
            for (int m = 8; m; m >>= 1) a += __shfl_xor(a, m);
            if (l16 == 0) {
                if (o < 12)       s_x[o] = a + bf[o];
                else if (o < 108) { const int t = o - 12; s_rx[t] = a + bf[t % 12]; }
                else              { const int g = o - 108; s_grad[g] = a + bg[g]; }
            }
        }
    }
    __syncthreads();

    if (tid < 96) {
        const int h = tid % 12;
        s_diff[tid] = s_x[h] - s_rx[tid];
    }
    __syncthreads();

    // dist logits + softmax (wave 0, lockstep) and logits (threads 0..79)
    if (tid < 8) {
        float nn = 0.0f;
        #pragma unroll
        for (int h = 0; h < 12; ++h) { const float d = s_diff[tid * 12 + h]; nn += d * d; }
        s_dist[tid] = -sqrtf(nn);
    }
    if (tid == 0) {
        float mx = s_dist[0];
        #pragma unroll
        for (int s = 1; s < 8; ++s) mx = fmaxf(mx, s_dist[s]);
        float e[8]; float tot = 0.0f;
        #pragma unroll
        for (int s = 0; s < 8; ++s) { e[s] = expf(s_dist[s] - mx); tot += e[s]; }
        #pragma unroll
        for (int s = 0; s < 8; ++s) s_dist[s] = e[s] / tot;
    }
    if (tid < 80) {
        const int s = tid / 10, c = tid - s * 10;
        const float* mrow = mem + (size_t)refs[n * 8 + s] * 10;
        float a = bm[c];
        #pragma unroll
        for (int k = 0; k < 10; ++k) a += mrow[k] * Wm[c * 10 + k];
        #pragma unroll
        for (int h = 0; h < 12; ++h) a += s_diff[s * 12 + h] * s_grad[h * 10 + c];
        s_logits[tid] = a;
    }
    __syncthreads();

    if (tid < 10) {
        float a = 0.0f;
        #pragma unroll
        for (int s = 0; s < 8; ++s) a += s_dist[s] * s_logits[s * 10 + tid];
        out[n * 10 + tid] = a;
    }
}

extern "C" void kernel_launch(void* const* d_in, const int* in_sizes, int n_in,
                              void* d_out, int out_size, void* d_ws, size_t ws_size,
                              hipStream_t stream) {
    const float* img   = (const float*)d_in[0];
    const float* train = (const float*)d_in[1];
    const float* mem   = (const float*)d_in[2];
    const float* w1    = (const float*)d_in[3];
    const float* b1    = (const float*)d_in[4];
    const float* w2    = (const float*)d_in[5];
    const float* b2    = (const float*)d_in[6];
    const float* Wf    = (const float*)d_in[7];
    const float* bf    = (const float*)d_in[8];
    const float* Wg    = (const float*)d_in[9];
    const float* bg    = (const float*)d_in[10];
    const float* Wm    = (const float*)d_in[11];
    const float* bm    = (const float*)d_in[12];
    // d_in[13] = idx (unused by the reference)
    const int*   refs  = (const int*)d_in[14];
    float* out = (float*)d_out;

    lenet_kernel<<<9216, 256, 0, stream>>>(img, train, refs, w1, b1, w2, b2);
    head_kernel<<<1024, 256, 0, stream>>>(mem, Wf, bf, Wg, bg, Wm, bm, refs, out);
}

// Round 2
// 854.494 us; speedup vs baseline: 1.8313x; 1.6944x over previous
//
#include <hip/hip_runtime.h>
#include <math.h>

// Static feature buffer: 9216 images x 400 feats.
// [0, 1024)    : features of img[n]
// [1024, 9216) : features of train[refs[n*8+s]] at offset 1024 + n*8 + s
__device__ float g_feat[9216 * 400];

// ---------------------------------------------------------------------------
// Kernel 1: LeNet trunk, one block per image.
// LDS layout (both tiles XOR-swizzled on 16B slots by row&7 to kill bank
// conflicts while keeping every read an aligned b128):
//   s_in : [3][32][32] floats, addr = ic*1024 + row*32 + ((slot^(row&7))<<2)+w
//   s_p1 : [6][14][32] floats (14 cols used), same swizzle keyed on row
// conv1: 98 threads, thread=(row-pair, 4-col tile); output channels processed
//        in TWO SEQUENTIAL HALVES of 3 (acc[3][2][4]=24 regs) so the working
//        set fits a 64-VGPR allocation -- round-1 version spilled 2.2 GB of
//        scratch traffic with acc[6][2][4].  Weights via lane-uniform loads.
// conv2: 160 threads, thread=(oc, oy), 10-wide row in registers,
//        pool2 fused via one __shfl_down.
// ---------------------------------------------------------------------------
__global__ __launch_bounds__(256, 2) void lenet_kernel(
    const float* __restrict__ img,     // (1024,3,32,32)
    const float* __restrict__ train,   // (50000,3,32,32)
    const int* __restrict__ refs,      // (1024,8)
    const float* __restrict__ w1, const float* __restrict__ b1,  // (6,3,5,5),(6)
    const float* __restrict__ w2, const float* __restrict__ b2)  // (16,6,5,5),(16)
{
    __shared__ __align__(16) float s_in[3 * 32 * 32];   // 12 KB, swizzled
    __shared__ __align__(16) float s_p1[6 * 14 * 32];   // 10.5 KB, swizzled

    const int blk = blockIdx.x;
    const int tid = threadIdx.x;

    const float* src = (blk < 1024)
        ? (img + (size_t)blk * 3072)
        : (train + (size_t)refs[blk - 1024] * 3072);
    const float4* src4 = (const float4*)src;

    // stage image, 3 float4 per thread, swizzled store (each f4 = one 16B slot)
    #pragma unroll
    for (int j = 0; j < 3; ++j) {
        const int i4 = tid + j * 256;            // 0..767
        const float4 v = src4[i4];
        const int ic   = i4 >> 8;
        const int row  = (i4 >> 3) & 31;
        const int slot = i4 & 7;
        *(float4*)(s_in + ic * 1024 + row * 32 + ((slot ^ (row & 7)) << 2)) = v;
    }
    __syncthreads();

    // ---- conv1 + relu + pool1 (fused). threads: (py 0..13, xt 0..6) = 98
    if (tid < 98) {
        const int py = tid / 7;
        const int xt = tid - py * 7;     // 4-col tile index; ox4 = 4*xt
        const int r0 = py * 2;           // first conv-output row of this thread

        #pragma unroll 1
        for (int och = 0; och < 2; ++och) {       // sequential oc-halves: low reg pressure
            float acc[3][2][4];
            #pragma unroll
            for (int o = 0; o < 3; ++o) {
                const float b = b1[och * 3 + o];  // lane-uniform -> scalar
                #pragma unroll
                for (int r = 0; r < 2; ++r)
                    #pragma unroll
                    for (int j = 0; j < 4; ++j) acc[o][r][j] = b;
            }

            #pragma unroll 1
            for (int ic = 0; ic < 3; ++ic) {
                const float* base = s_in + ic * 1024;
                const float* wic  = w1 + och * 3 * 75 + ic * 25;  // uniform weight base
                float A[8], B[8];
                {
                    const int row = r0, r7 = row & 7;
                    const float4 lo = *(const float4*)(base + row * 32 + ((xt ^ r7) << 2));
                    const float4 hi = *(const float4*)(base + row * 32 + (((xt + 1) ^ r7) << 2));
                    A[0]=lo.x; A[1]=lo.y; A[2]=lo.z; A[3]=lo.w;
                    A[4]=hi.x; A[5]=hi.y; A[6]=hi.z; A[7]=hi.w;
                }
                #pragma unroll
                for (int ky = 0; ky < 5; ++ky) {
                    const int row = r0 + ky + 1, r7 = row & 7;
                    const float4 lo = *(const float4*)(base + row * 32 + ((xt ^ r7) << 2));
                    const float4 hi = *(const float4*)(base + row * 32 + (((xt + 1) ^ r7) << 2));
                    B[0]=lo.x; B[1]=lo.y; B[2]=lo.z; B[3]=lo.w;
                    B[4]=hi.x; B[5]=hi.y; B[6]=hi.z; B[7]=hi.w;
                    #pragma unroll
                    for (int o = 0; o < 3; ++o) {
                        #pragma unroll
                        for (int kx = 0; kx < 5; ++kx) {
                            const float w = wic[o * 75 + ky * 5 + kx];  // uniform -> s_load
                            #pragma unroll
                            for (int j = 0; j < 4; ++j) {
                                acc[o][0][j] = fmaf(A[j + kx], w, acc[o][0][j]);  // row r0   <- in r0+ky
                                acc[o][1][j] = fmaf(B[j + kx], w, acc[o][1][j]);  // row r0+1 <- in r0+ky+1
                            }
                        }
                    }
                    #pragma unroll
                    for (int q = 0; q < 8; ++q) A[q] = B[q];  // input-row reuse across ky
                }
            }

            // 2x2 pool + relu -> s_p1[oc][py][2*xt .. 2*xt+1] (swizzled, float2)
            const int r7 = py & 7;
            const int px0 = xt * 2;   // even -> pair stays inside one 16B slot
            #pragma unroll
            for (int o = 0; o < 3; ++o) {
                const int oc = och * 3 + o;
                const float m0 = fmaxf(fmaxf(acc[o][0][0], acc[o][0][1]),
                                       fmaxf(acc[o][1][0], acc[o][1][1]));
                const float m1 = fmaxf(fmaxf(acc[o][0][2], acc[o][0][3]),
                                       fmaxf(acc[o][1][2], acc[o][1][3]));
                float* d = s_p1 + oc * 448 + py * 32 + (((px0 >> 2) ^ r7) << 2) + (px0 & 3);
                *(float2*)d = make_float2(fmaxf(m0, 0.0f), fmaxf(m1, 0.0f));
            }
        }
    }
    __syncthreads();

    // ---- conv2 + relu + pool2 (fused). threads: (oc 0..15, oy 0..9) = 160
    if (tid < 160) {
        const int oc = tid / 10;
        const int oy = tid - oc * 10;

        float acc[10];
        {
            const float b = b2[oc];
            #pragma unroll
            for (int j = 0; j < 10; ++j) acc[j] = b;
        }
        const float* wrow = w2 + oc * 150;
        #pragma unroll 1
        for (int ic = 0; ic < 6; ++ic) {
            const float* base = s_p1 + ic * 448;
            const float* wic  = wrow + ic * 25;
            #pragma unroll
            for (int ky = 0; ky < 5; ++ky) {
                const int row = oy + ky, r7 = row & 7;
                const float* rb = base + row * 32;
                float in[14];
                const float4 q0 = *(const float4*)(rb + ((0 ^ r7) << 2));
                const float4 q1 = *(const float4*)(rb + ((1 ^ r7) << 2));
                const float4 q2 = *(const float4*)(rb + ((2 ^ r7) << 2));
                const float2 q3 = *(const float2*)(rb + ((3 ^ r7) << 2));
                in[0]=q0.x;  in[1]=q0.y;  in[2]=q0.z;  in[3]=q0.w;
                in[4]=q1.x;  in[5]=q1.y;  in[6]=q1.z;  in[7]=q1.w;
                in[8]=q2.x;  in[9]=q2.y;  in[10]=q2.z; in[11]=q2.w;
                in[12]=q3.x; in[13]=q3.y;
                #pragma unroll
                for (int kx = 0; kx < 5; ++kx) {
                    const float w = wic[ky * 5 + kx];   // per-lane (oc-varying), L1-hot
                    #pragma unroll
                    for (int j = 0; j < 10; ++j)
                        acc[j] = fmaf(in[j + kx], w, acc[j]);
                }
            }
        }
        // horizontal pool in-lane, vertical via neighbor lane (oy, oy+1 same wave)
        float v[5];
        #pragma unroll
        for (int k = 0; k < 5; ++k) v[k] = fmaxf(acc[2 * k], acc[2 * k + 1]);
        float* fo = g_feat + (size_t)blk * 400 + oc * 25 + (oy >> 1) * 5;
        #pragma unroll
        for (int k = 0; k < 5; ++k) {
            const float m = fmaxf(v[k], __shfl_down(v[k], 1));
            if ((oy & 1) == 0) fo[k] = fmaxf(m, 0.0f);
        }
    }
}

// ---------------------------------------------------------------------------
// Kernel 2: head. One block per n. Phase A computes the 228 length-400 dots
// (x:12, ref_x:96, grad:120) with 16-lane k-parallel float4 groups so both
// weight and feature traffic is coalesced; shuffle-reduce inside the group.
// ---------------------------------------------------------------------------
__global__ __launch_bounds__(256) void head_kernel(
    const float* __restrict__ mem,   // (50000,10)
    const float* __restrict__ Wf, const float* __restrict__ bf,   // (12,400),(12)
    const float* __restrict__ Wg, const float* __restrict__ bg,   // (120,400),(120)
    const float* __restrict__ Wm, const float* __restrict__ bm,   // (10,10),(10)
    const int* __restrict__ refs,    // (1024,8)
    float* __restrict__ out)         // (1024,10)
{
    const int n = blockIdx.x;
    const int tid = threadIdx.x;

    __shared__ __align__(16) float s_feat[400];
    __shared__ __align__(16) float s_rfeat[8 * 400];
    __shared__ float s_x[12];
    __shared__ float s_rx[96];       // t = s*12 + h
    __shared__ float s_grad[120];    // g = h*10 + c
    __shared__ float s_diff[96];
    __shared__ float s_dist[8];
    __shared__ float s_logits[80];

    const float4* f4 = (const float4*)(g_feat + (size_t)n * 400);
    for (int i = tid; i < 100; i += 256) ((float4*)s_feat)[i] = f4[i];
    const float4* r4 = (const float4*)(g_feat + (size_t)(1024 + n * 8) * 400);
    for (int i = tid; i < 800; i += 256) ((float4*)s_rfeat)[i] = r4[i];
    __syncthreads();

    // Phase A: outputs o: [0,12)=x[h], [12,108)=rx[s*12+h], [108,228)=grad[g]
    const int grp = tid >> 4;   // 16 groups
    const int l16 = tid & 15;
    for (int r = 0; r < 15; ++r) {
        const int o = r * 16 + grp;
        if (o < 228) {
            const float* w;
            const float* f;
            if (o < 12)       { w = Wf + o * 400;              f = s_feat; }
            else if (o < 108) { const int t = o - 12;
                                w = Wf + (t % 12) * 400;       f = s_rfeat + (t / 12) * 400; }
            else              { const int g = o - 108;
                                w = Wg + g * 400;              f = s_feat; }
            float a = 0.0f;
            #pragma unroll
            for (int it = 0; it < 7; ++it) {
                const int k = it * 64 + l16 * 4;
                if (k < 400) {
                    const float4 wv = *(const float4*)(w + k);
                    const float4 fv = *(const float4*)(f + k);
                    a = fmaf(wv.x, fv.x, a); a = fmaf(wv.y, fv.y, a);
                    a = fmaf(wv.z, fv.z, a); a = fmaf(wv.w, fv.w, a);
                }
            }
            #pragma unroll
            for (int m = 8; m; m >>= 1) a += __shfl_xor(a, m);
            if (l16 == 0) {
                if (o < 12)       s_x[o] = a + bf[o];
                else if (o < 108) { const int t = o - 12; s_rx[t] = a + bf[t % 12]; }
                else              { const int g = o - 108; s_grad[g] = a + bg[g]; }
            }
        }
    }
    __syncthreads();

    if (tid < 96) {
        const int h = tid % 12;
        s_diff[tid] = s_x[h] - s_rx[tid];
    }
    __syncthreads();

    // dist logits + softmax (wave 0, lockstep) and logits (threads 0..79)
    if (tid < 8) {
        float nn = 0.0f;
        #pragma unroll
        for (int h = 0; h < 12; ++h) { const float d = s_diff[tid * 12 + h]; nn += d * d; }
        s_dist[tid] = -sqrtf(nn);
    }
    if (tid == 0) {
        float mx = s_dist[0];
        #pragma unroll
        for (int s = 1; s < 8; ++s) mx = fmaxf(mx, s_dist[s]);
        float e[8]; float tot = 0.0f;
        #pragma unroll
        for (int s = 0; s < 8; ++s) { e[s] = expf(s_dist[s] - mx); tot += e[s]; }
        #pragma unroll
        for (int s = 0; s < 8; ++s) s_dist[s] = e[s] / tot;
    }
    if (tid < 80) {
        const int s = tid / 10, c = tid - s * 10;
        const float* mrow = mem + (size_t)refs[n * 8 + s] * 10;
        float a = bm[c];
        #pragma unroll
        for (int k = 0; k < 10; ++k) a += mrow[k] * Wm[c * 10 + k];
        #pragma unroll
        for (int h = 0; h < 12; ++h) a += s_diff[s * 12 + h] * s_grad[h * 10 + c];
        s_logits[tid] = a;
    }
    __syncthreads();

    if (tid < 10) {
        float a = 0.0f;
        #pragma unroll
        for (int s = 0; s < 8; ++s) a += s_dist[s] * s_logits[s * 10 + tid];
        out[n * 10 + tid] = a;
    }
}

extern "C" void kernel_launch(void* const* d_in, const int* in_sizes, int n_in,
                              void* d_out, int out_size, void* d_ws, size_t ws_size,
                              hipStream_t stream) {
    const float* img   = (const float*)d_in[0];
    const float* train = (const float*)d_in[1];
    const float* mem   = (const float*)d_in[2];
    const float* w1    = (const float*)d_in[3];
    const float* b1    = (const float*)d_in[4];
    const float* w2    = (const float*)d_in[5];
    const float* b2    = (const float*)d_in[6];
    const float* Wf    = (const float*)d_in[7];
    const float* bf    = (const float*)d_in[8];
    const float* Wg    = (const float*)d_in[9];
    const float* bg    = (const float*)d_in[10];
    const float* Wm    = (const float*)d_in[11];
    const float* bm    = (const float*)d_in[12];
    // d_in[13] = idx (unused by the reference)
    const int*   refs  = (const int*)d_in[14];
    float* out = (float*)d_out;

    lenet_kernel<<<9216, 256, 0, stream>>>(img, train, refs, w1, b1, w2, b2);
    head_kernel<<<1024, 256, 0, stream>>>(mem, Wf, bf, Wg, bg, Wm, bm, refs, out);
}